// Round 10
// baseline (174.841 us; speedup 1.0000x reference)
//
#include <hip/hip_runtime.h>
#include <hip/hip_bf16.h>

#define T_TOK 16384
#define D_DIM 1024
#define E_EXP 8
#define NPAIR 28

#define BM 128
#define BN 128
#define BK 64            // 128 B/row in bf16
#define NT_K (D_DIM / BK)

#define CNT_STRIDE 64    // pad pair counters to 256B apart

typedef __attribute__((ext_vector_type(4))) float f32x4;
typedef __attribute__((ext_vector_type(2))) float f32x2;
typedef __attribute__((ext_vector_type(8))) short bf16x8;
typedef __attribute__((ext_vector_type(4))) unsigned short u16x4;

static __device__ __forceinline__ unsigned short f2bf(float f) {
    unsigned int u = __float_as_uint(f);
    unsigned int r = 0x7FFFu + ((u >> 16) & 1u);
    return (unsigned short)((u + r) >> 16);
}

// direct-to-LDS 16B async copy: global src per-lane, LDS dest = uniform base + lane*16
#define GLOAD_LDS16(gp, lp) \
    __builtin_amdgcn_global_load_lds( \
        (const __attribute__((address_space(1))) void*)(gp), \
        (__attribute__((address_space(3))) void*)(lp), 16, 0, 0)

// ---------------- fused router (blocks 0..255) + expert_w->bf16 (blocks 256..383) ----
#define RTOK 64
#define RBLK 256
#define CBLK 128
__global__ __launch_bounds__(512) void fused_router_kernel(
    const float* __restrict__ x, const float* __restrict__ gate_w,
    const float* __restrict__ gate_b, float* __restrict__ out_logits,
    float* __restrict__ out_sel, int* __restrict__ counts,
    int* __restrict__ pair_token, f32x2* __restrict__ pair_w,
    unsigned short* __restrict__ xbf,
    const float* __restrict__ expert_w, unsigned short* __restrict__ wbf) {
    const int tid = threadIdx.x;
    if (blockIdx.x >= RBLK) {
        // -------- convert region: expert_w fp32 -> bf16 --------
        const int b = blockIdx.x - RBLK;
        const int n4 = (E_EXP * D_DIM * D_DIM) / 4;
        for (int i = b * 512 + tid; i < n4; i += CBLK * 512) {
            f32x4 v = ((const f32x4*)expert_w)[i];
            u16x4 p;
            p[0] = f2bf(v[0]); p[1] = f2bf(v[1]); p[2] = f2bf(v[2]); p[3] = f2bf(v[3]);
            ((u16x4*)wbf)[i] = p;
        }
        return;
    }
    // -------- router region: 64 tokens/block, 8 waves --------
    __shared__ float gw[E_EXP][D_DIM];          // 32 KB
    __shared__ float gb_s[E_EXP];
    __shared__ float logits_s[RTOK][E_EXP];     // 2 KB
    __shared__ int   cnt_local[NPAIR];
    __shared__ int   gbase[NPAIR];
    __shared__ int   ent_p[RTOK];
    __shared__ int   ent_pos[RTOK];
    __shared__ f32x2 ent_w[RTOK];

    for (int i = tid; i < E_EXP * D_DIM; i += 512) gw[0][i] = gate_w[i];
    if (tid < E_EXP) gb_s[tid] = gate_b[tid];
    if (tid < NPAIR) cnt_local[tid] = 0;
    __syncthreads();

    const int lane = tid & 63, wv = tid >> 6;   // 8 waves
    // phase 1: logits via coalesced row streaming (wave per token, 8 tokens/wave)
    for (int j = 0; j < RTOK / 8; ++j) {
        const int jt = wv * (RTOK / 8) + j;
        const int t = blockIdx.x * RTOK + jt;
        const float* xrow = x + (size_t)t * D_DIM;
        unsigned short* xbrow = xbf + (size_t)t * D_DIM;
        float acc[E_EXP] = {};
        #pragma unroll
        for (int c = 0; c < 4; ++c) {
            const int col = c * 256 + lane * 4;
            f32x4 xv = *(const f32x4*)(xrow + col);
            u16x4 pk;
            pk[0] = f2bf(xv[0]); pk[1] = f2bf(xv[1]); pk[2] = f2bf(xv[2]); pk[3] = f2bf(xv[3]);
            *(u16x4*)(xbrow + col) = pk;
            #pragma unroll
            for (int e = 0; e < E_EXP; ++e) {
                f32x4 gv = *(const f32x4*)(&gw[e][col]);
                acc[e] += xv[0] * gv[0] + xv[1] * gv[1] + xv[2] * gv[2] + xv[3] * gv[3];
            }
        }
        #pragma unroll
        for (int e = 0; e < E_EXP; ++e) {
            float v = acc[e];
            #pragma unroll
            for (int off = 32; off > 0; off >>= 1) v += __shfl_xor(v, off, 64);
            acc[e] = v;
        }
        if (lane == 0) {
            #pragma unroll
            for (int e = 0; e < E_EXP; ++e) logits_s[jt][e] = acc[e] + gb_s[e];
        }
    }
    __syncthreads();
    // phase 2: one thread per token: softmax, top-2, pair bookkeeping
    if (tid < RTOK) {
        const int t = blockIdx.x * RTOK + tid;
        float l[E_EXP], p[E_EXP];
        float m = -1e30f;
        #pragma unroll
        for (int e = 0; e < E_EXP; ++e) { l[e] = logits_s[tid][e]; m = fmaxf(m, l[e]); }
        float s = 0.f;
        #pragma unroll
        for (int e = 0; e < E_EXP; ++e) { p[e] = expf(l[e] - m); s += p[e]; }
        #pragma unroll
        for (int e = 0; e < E_EXP; ++e) p[e] /= s;
        // top-2 on probs, strict > => lowest index wins ties (matches jax.lax.top_k)
        int e0 = 0; float p0 = p[0];
        #pragma unroll
        for (int e = 1; e < E_EXP; ++e) if (p[e] > p0) { p0 = p[e]; e0 = e; }
        int e1 = -1; float p1 = -1e30f;
        #pragma unroll
        for (int e = 0; e < E_EXP; ++e) if (e != e0 && p[e] > p1) { p1 = p[e]; e1 = e; }
        float denom = p0 + p1;
        float w0 = p0 / denom, w1 = p1 / denom;
        out_sel[t * 2 + 0] = (float)e0;
        out_sel[t * 2 + 1] = (float)e1;
        int lo = min(e0, e1), hi = max(e0, e1);
        float wl = (e0 < e1) ? w0 : w1;
        float wh = (e0 < e1) ? w1 : w0;
        int pp = (lo * (15 - lo)) / 2 + (hi - lo - 1);   // triangular index [0,28)
        int pos = atomicAdd(&cnt_local[pp], 1);          // LDS atomic: cheap
        ent_p[tid] = pp; ent_pos[tid] = pos;
        f32x2 wv2; wv2[0] = wl; wv2[1] = wh;
        ent_w[tid] = wv2;
    }
    __syncthreads();
    if (tid < NPAIR) gbase[tid] = atomicAdd(&counts[tid * CNT_STRIDE], cnt_local[tid]);
    if (tid < RTOK * E_EXP / 4) {
        f32x4 v = ((const f32x4*)&logits_s[0][0])[tid];
        ((f32x4*)(out_logits + (size_t)blockIdx.x * RTOK * E_EXP))[tid] = v;
    }
    __syncthreads();
    if (tid < RTOK) {
        int pp = ent_p[tid];
        int pos = gbase[pp] + ent_pos[tid];
        pair_token[pp * T_TOK + pos] = blockIdx.x * RTOK + tid;
        pair_w[pp * T_TOK + pos] = ent_w[tid];
    }
}

// ---------------- pair-grouped GEMM, 8 waves, fine-phase + counted vmcnt ----------
// out[t] = wl*(Wlo x+blo) + wh*(Whi x+bhi).  BK=64, double-buffered LDS (96 KB),
// 2-deep lookahead: each K-tile issues next tile's 6 gloads/thread, waits
// vmcnt(6) (next tile's 6 stay in flight across the barrier).  Per K-tile:
// 2 phases (kk halves) x {8 ds_read_b128 -> 16 MFMA in setprio(1)}, 3 barriers.
// Both-sides XOR swizzle (chunk ^ (row&7)); plain stores, no atomics.
// Fused tile scheduling via wave-0 prefix scan; XCD-chunked flat mapping.
__global__ __launch_bounds__(512) void moe_gemm_kernel(
    const unsigned short* __restrict__ xbf, const unsigned short* __restrict__ wbf,
    const float* __restrict__ expert_b, const int* __restrict__ counts,
    const int* __restrict__ pair_token, const f32x2* __restrict__ pair_w,
    float* __restrict__ out) {
    const int flat = blockIdx.x;
    const int cls = flat & 7;          // XCD class
    const int nt  = (flat >> 3) & 7;   // n-tile
    const int sup = flat >> 6;
    const int gidx = sup * 8 + cls;    // tile-list index

    __shared__ int hdr[5];             // lo, hi, m_base, cnt, pair
    const int tid = threadIdx.x;
    if (tid < 64) {
        int c = (tid < NPAIR) ? counts[tid * CNT_STRIDE] : 0;
        int ntp = (c + BM - 1) >> 7;              // tiles for this pair
        int s = ntp;
        #pragma unroll
        for (int off = 1; off < 64; off <<= 1) {  // inclusive scan
            int v = __shfl_up(s, off, 64);
            if (tid >= off) s += v;
        }
        int excl = s - ntp;
        bool mine = (tid < NPAIR) && (gidx >= excl) && (gidx < s);
        unsigned long long mb = __ballot(mine);
        int p = mb ? (__ffsll((long long)mb) - 1) : 0;
        int exclp = __shfl(excl, p, 64);
        int cp = __shfl(c, p, 64);
        if (tid == 0) {
            if (mb == 0) { hdr[0] = -1; }
            else {
                int lo = 0, q = p;
                while (q >= 7 - lo) { q -= 7 - lo; ++lo; }
                hdr[0] = lo; hdr[1] = lo + 1 + q;
                hdr[2] = (gidx - exclp) * BM; hdr[3] = cp; hdr[4] = p;
            }
        }
    }
    __syncthreads();
    const int lo = hdr[0];
    if (lo < 0) return;                 // uniform: no tile for this block
    const int hi = hdr[1];
    const int m_base = hdr[2];
    const int cnt = hdr[3];
    const int p = hdr[4];
    const int n_base = nt * BN;

    __shared__ unsigned short As[2][BM * BK];    // 32 KB each pair of buffers
    __shared__ unsigned short B0s[2][BM * BK];
    __shared__ unsigned short B1s[2][BM * BK];
    __shared__ int tok_s[BM];
    __shared__ f32x2 w_s[BM];

    if (tid < BM) {
        int m = m_base + tid;
        int mc = (m < cnt) ? m : (cnt - 1);  // clamp: garbage rows skipped in epilogue
        tok_s[tid] = pair_token[p * T_TOK + mc];
        w_s[tid]   = pair_w[p * T_TOK + mc];
    }
    __syncthreads();

    const int lane = tid & 63;
    const int wv = tid >> 6;                  // 8 waves: 2(m) x 4(n)
    const int wm = wv >> 2, wn = wv & 3;      // wave tile 64(m) x 32(n)
    const int lr = lane & 15, lk = lane >> 4;

    // staging: thread covers rows r and r+64 (chunk tid&7) of each matrix
    const int r = tid >> 3;
    const int swcol = 8 * ((tid & 7) ^ (r & 7));     // swizzled source col (elems)
    const unsigned short* wb0 = wbf + ((size_t)lo << 20);
    const unsigned short* wb1 = wbf + ((size_t)hi << 20);
    const unsigned short* ag0  = xbf + (size_t)tok_s[r] * D_DIM + swcol;
    const unsigned short* ag1  = xbf + (size_t)tok_s[64 + r] * D_DIM + swcol;
    const unsigned short* b0g0 = wb0 + (size_t)(n_base + r) * D_DIM + swcol;
    const unsigned short* b0g1 = wb0 + (size_t)(n_base + 64 + r) * D_DIM + swcol;
    const unsigned short* b1g0 = wb1 + (size_t)(n_base + r) * D_DIM + swcol;
    const unsigned short* b1g1 = wb1 + (size_t)(n_base + 64 + r) * D_DIM + swcol;
    const int l0 = (wv * 64) * 8;             // wave-uniform LDS elem offsets
    const int l1 = (512 + wv * 64) * 8;

    f32x4 acc0[4][2] = {};
    f32x4 acc1[4][2] = {};

#define STAGE(buf, k0s) do { \
        GLOAD_LDS16(ag0  + (k0s), &As[(buf)][l0]);  GLOAD_LDS16(ag1  + (k0s), &As[(buf)][l1]); \
        GLOAD_LDS16(b0g0 + (k0s), &B0s[(buf)][l0]); GLOAD_LDS16(b0g1 + (k0s), &B0s[(buf)][l1]); \
        GLOAD_LDS16(b1g0 + (k0s), &B1s[(buf)][l0]); GLOAD_LDS16(b1g1 + (k0s), &B1s[(buf)][l1]); \
    } while (0)

#define PHASE(buf, kk) do { \
        const char* Ab = (const char*)&As[(buf)][0]; \
        const char* Bb = (const char*)&B0s[(buf)][0]; \
        const char* Cb = (const char*)&B1s[(buf)][0]; \
        bf16x8 a[4], b[2], c[2]; \
        _Pragma("unroll") \
        for (int m = 0; m < 4; ++m) { \
            int R = wm * 64 + m * 16 + lr; \
            a[m] = *(const bf16x8*)(Ab + R * 128 + (((kk) * 64 + lk * 16) ^ ((R & 7) << 4))); \
        } \
        _Pragma("unroll") \
        for (int n = 0; n < 2; ++n) { \
            int R = wn * 32 + n * 16 + lr; \
            int cb = ((kk) * 64 + lk * 16) ^ ((R & 7) << 4); \
            b[n] = *(const bf16x8*)(Bb + R * 128 + cb); \
            c[n] = *(const bf16x8*)(Cb + R * 128 + cb); \
        } \
        __builtin_amdgcn_s_setprio(1); \
        _Pragma("unroll") \
        for (int m = 0; m < 4; ++m) \
            _Pragma("unroll") \
            for (int n = 0; n < 2; ++n) \
                acc0[m][n] = __builtin_amdgcn_mfma_f32_16x16x32_bf16(a[m], b[n], acc0[m][n], 0, 0, 0); \
        _Pragma("unroll") \
        for (int m = 0; m < 4; ++m) \
            _Pragma("unroll") \
            for (int n = 0; n < 2; ++n) \
                acc1[m][n] = __builtin_amdgcn_mfma_f32_16x16x32_bf16(a[m], c[n], acc1[m][n], 0, 0, 0); \
        __builtin_amdgcn_s_setprio(0); \
    } while (0)

    // prologue: tile 0 into buffer 0 (6 loads/thread in flight)
    STAGE(0, 0);

    #pragma unroll 1
    for (int t = 0; t < NT_K - 1; ++t) {
        const int buf = t & 1;
        STAGE(buf ^ 1, (t + 1) * BK);                      // 6 more in flight
        asm volatile("s_waitcnt vmcnt(6)" ::: "memory");   // tile t landed (mine)
        __builtin_amdgcn_s_barrier();                      // tile t landed (all)
        PHASE(buf, 0);
        __builtin_amdgcn_s_barrier();                      // phase lockstep
        PHASE(buf, 1);
        asm volatile("s_waitcnt lgkmcnt(0)" ::: "memory"); // my reads of buf done
        __builtin_amdgcn_s_barrier();                      // buf free to overwrite
    }
    asm volatile("s_waitcnt vmcnt(0)" ::: "memory");       // last tile landed
    __builtin_amdgcn_s_barrier();
    PHASE(1, 0);
    __builtin_amdgcn_s_barrier();
    PHASE(1, 1);
#undef PHASE
#undef STAGE

    // epilogue: out[t, gn] = wl*(acc0+blo) + wh*(acc1+bhi)   (plain stores, no atomics)
    float blo[2], bhi[2];
    #pragma unroll
    for (int n = 0; n < 2; ++n) {
        int gn = n_base + wn * 32 + n * 16 + lr;
        blo[n] = expert_b[lo * D_DIM + gn];
        bhi[n] = expert_b[hi * D_DIM + gn];
    }
    #pragma unroll
    for (int m = 0; m < 4; ++m) {
        #pragma unroll
        for (int j = 0; j < 4; ++j) {
            int mi = wm * 64 + m * 16 + lk * 4 + j;
            if (m_base + mi >= cnt) continue;
            int tk = tok_s[mi];
            f32x2 wgt = w_s[mi];
            size_t obase = (size_t)tk * D_DIM + n_base + wn * 32 + lr;
            #pragma unroll
            for (int n = 0; n < 2; ++n)
                out[obase + n * 16] = wgt[0] * (acc0[m][n][j] + blo[n])
                                    + wgt[1] * (acc1[m][n][j] + bhi[n]);
        }
    }
}

extern "C" void kernel_launch(void* const* d_in, const int* in_sizes, int n_in,
                              void* d_out, int out_size, void* d_ws, size_t ws_size,
                              hipStream_t stream) {
    const float* x        = (const float*)d_in[0];
    const float* gate_w   = (const float*)d_in[1];
    const float* gate_b   = (const float*)d_in[2];
    const float* expert_w = (const float*)d_in[3];
    const float* expert_b = (const float*)d_in[4];

    float* out        = (float*)d_out;                      // [T, D]
    float* out_logits = out + (size_t)T_TOK * D_DIM;        // [T, E]
    float* out_sel    = out_logits + (size_t)T_TOK * E_EXP; // [T, 2] as float

    char* ws = (char*)d_ws;
    unsigned short* wbf = (unsigned short*)ws;                         // 16 MB
    unsigned short* xbf = (unsigned short*)(ws + 16777216);            // 32 MB
    size_t off = 50331648;
    int*   counts     = (int*)(ws + off);                              // 28*64 ints = 7 KB
    int*   pair_token = (int*)(ws + off + 16384);                      // 28*T*4 = 1.75 MB
    f32x2* pair_w     = (f32x2*)(ws + off + 16384 + 1835008);          // 28*T*8 = 3.5 MB

    hipMemsetAsync(counts, 0, NPAIR * CNT_STRIDE * sizeof(int), stream);

    fused_router_kernel<<<RBLK + CBLK, 512, 0, stream>>>(
        x, gate_w, gate_b, out_logits, out_sel, counts, pair_token, pair_w,
        xbf, expert_w, wbf);
    // sup(20) x nt(8) x cls(8): gidx in [0,160), covers max 155 tiles
    moe_gemm_kernel<<<20 * 64, 512, 0, stream>>>(xbf, wbf, expert_b, counts,
                                                 pair_token, pair_w, out);
}

// Round 11
// 135.225 us; speedup vs baseline: 1.2930x; 1.2930x over previous
//
#include <hip/hip_runtime.h>
#include <hip/hip_bf16.h>

#define T_TOK 16384
#define D_DIM 1024
#define E_EXP 8
#define NPAIR 28

#define BM 128
#define BN 128
#define BK 64            // 128 B/row in bf16

#define CNT_STRIDE 64    // pad pair counters to 256B apart

typedef __attribute__((ext_vector_type(4))) float f32x4;
typedef __attribute__((ext_vector_type(2))) float f32x2;
typedef __attribute__((ext_vector_type(8))) short bf16x8;
typedef __attribute__((ext_vector_type(4))) unsigned short u16x4;

static __device__ __forceinline__ unsigned short f2bf(float f) {
    unsigned int u = __float_as_uint(f);
    unsigned int r = 0x7FFFu + ((u >> 16) & 1u);
    return (unsigned short)((u + r) >> 16);
}

// direct-to-LDS 16B async copy: global src per-lane, LDS dest = uniform base + lane*16
#define GLOAD_LDS16(gp, lp) \
    __builtin_amdgcn_global_load_lds( \
        (const __attribute__((address_space(1))) void*)(gp), \
        (__attribute__((address_space(3))) void*)(lp), 16, 0, 0)

// ---------------- fused router (blocks 0..255) + expert_w->bf16 (blocks 256..383) ----
#define RTOK 64
#define RBLK 256
#define CBLK 128
__global__ __launch_bounds__(512) void fused_router_kernel(
    const float* __restrict__ x, const float* __restrict__ gate_w,
    const float* __restrict__ gate_b, float* __restrict__ out_logits,
    float* __restrict__ out_sel, int* __restrict__ counts,
    int* __restrict__ pair_token, f32x2* __restrict__ pair_w,
    unsigned short* __restrict__ xbf,
    const float* __restrict__ expert_w, unsigned short* __restrict__ wbf) {
    const int tid = threadIdx.x;
    if (blockIdx.x >= RBLK) {
        // -------- convert region: expert_w fp32 -> bf16 --------
        const int b = blockIdx.x - RBLK;
        const int n4 = (E_EXP * D_DIM * D_DIM) / 4;
        for (int i = b * 512 + tid; i < n4; i += CBLK * 512) {
            f32x4 v = ((const f32x4*)expert_w)[i];
            u16x4 p;
            p[0] = f2bf(v[0]); p[1] = f2bf(v[1]); p[2] = f2bf(v[2]); p[3] = f2bf(v[3]);
            ((u16x4*)wbf)[i] = p;
        }
        return;
    }
    // -------- router region: 64 tokens/block, 8 waves --------
    __shared__ float gw[E_EXP][D_DIM];          // 32 KB
    __shared__ float gb_s[E_EXP];
    __shared__ float logits_s[RTOK][E_EXP];     // 2 KB
    __shared__ int   cnt_local[NPAIR];
    __shared__ int   gbase[NPAIR];
    __shared__ int   ent_p[RTOK];
    __shared__ int   ent_pos[RTOK];
    __shared__ f32x2 ent_w[RTOK];

    for (int i = tid; i < E_EXP * D_DIM; i += 512) gw[0][i] = gate_w[i];
    if (tid < E_EXP) gb_s[tid] = gate_b[tid];
    if (tid < NPAIR) cnt_local[tid] = 0;
    __syncthreads();

    const int lane = tid & 63, wv = tid >> 6;   // 8 waves
    // phase 1: logits via coalesced row streaming (wave per token, 8 tokens/wave)
    for (int j = 0; j < RTOK / 8; ++j) {
        const int jt = wv * (RTOK / 8) + j;
        const int t = blockIdx.x * RTOK + jt;
        const float* xrow = x + (size_t)t * D_DIM;
        unsigned short* xbrow = xbf + (size_t)t * D_DIM;
        float acc[E_EXP] = {};
        #pragma unroll
        for (int c = 0; c < 4; ++c) {
            const int col = c * 256 + lane * 4;
            f32x4 xv = *(const f32x4*)(xrow + col);
            u16x4 pk;
            pk[0] = f2bf(xv[0]); pk[1] = f2bf(xv[1]); pk[2] = f2bf(xv[2]); pk[3] = f2bf(xv[3]);
            *(u16x4*)(xbrow + col) = pk;
            #pragma unroll
            for (int e = 0; e < E_EXP; ++e) {
                f32x4 gv = *(const f32x4*)(&gw[e][col]);
                acc[e] += xv[0] * gv[0] + xv[1] * gv[1] + xv[2] * gv[2] + xv[3] * gv[3];
            }
        }
        #pragma unroll
        for (int e = 0; e < E_EXP; ++e) {
            float v = acc[e];
            #pragma unroll
            for (int off = 32; off > 0; off >>= 1) v += __shfl_xor(v, off, 64);
            acc[e] = v;
        }
        if (lane == 0) {
            #pragma unroll
            for (int e = 0; e < E_EXP; ++e) logits_s[jt][e] = acc[e] + gb_s[e];
        }
    }
    __syncthreads();
    // phase 2: one thread per token: softmax, top-2, pair bookkeeping
    if (tid < RTOK) {
        const int t = blockIdx.x * RTOK + tid;
        float l[E_EXP], p[E_EXP];
        float m = -1e30f;
        #pragma unroll
        for (int e = 0; e < E_EXP; ++e) { l[e] = logits_s[tid][e]; m = fmaxf(m, l[e]); }
        float s = 0.f;
        #pragma unroll
        for (int e = 0; e < E_EXP; ++e) { p[e] = expf(l[e] - m); s += p[e]; }
        #pragma unroll
        for (int e = 0; e < E_EXP; ++e) p[e] /= s;
        // top-2 on probs, strict > => lowest index wins ties (matches jax.lax.top_k)
        int e0 = 0; float p0 = p[0];
        #pragma unroll
        for (int e = 1; e < E_EXP; ++e) if (p[e] > p0) { p0 = p[e]; e0 = e; }
        int e1 = -1; float p1 = -1e30f;
        #pragma unroll
        for (int e = 0; e < E_EXP; ++e) if (e != e0 && p[e] > p1) { p1 = p[e]; e1 = e; }
        float denom = p0 + p1;
        float w0 = p0 / denom, w1 = p1 / denom;
        out_sel[t * 2 + 0] = (float)e0;
        out_sel[t * 2 + 1] = (float)e1;
        int lo = min(e0, e1), hi = max(e0, e1);
        float wl = (e0 < e1) ? w0 : w1;
        float wh = (e0 < e1) ? w1 : w0;
        int pp = (lo * (15 - lo)) / 2 + (hi - lo - 1);   // triangular index [0,28)
        int pos = atomicAdd(&cnt_local[pp], 1);          // LDS atomic: cheap
        ent_p[tid] = pp; ent_pos[tid] = pos;
        f32x2 wv2; wv2[0] = wl; wv2[1] = wh;
        ent_w[tid] = wv2;
    }
    __syncthreads();
    if (tid < NPAIR) gbase[tid] = atomicAdd(&counts[tid * CNT_STRIDE], cnt_local[tid]);
    if (tid < RTOK * E_EXP / 4) {
        f32x4 v = ((const f32x4*)&logits_s[0][0])[tid];
        ((f32x4*)(out_logits + (size_t)blockIdx.x * RTOK * E_EXP))[tid] = v;
    }
    __syncthreads();
    if (tid < RTOK) {
        int pp = ent_p[tid];
        int pos = gbase[pp] + ent_pos[tid];
        pair_token[pp * T_TOK + pos] = blockIdx.x * RTOK + tid;
        pair_w[pp * T_TOK + pos] = ent_w[tid];
    }
}

// ---------------- pair-grouped GEMM (R9-proven structure; K-loop schedule FROZEN) ----
// out[t] = wl*(Wlo x+blo) + wh*(Whi x+bhi).  Single-buffer BK=64, A+B0+B1 staged
// per K-step via global_load_lds w=16; both-sides XOR swizzle; plain stores.
// Measured (R9): 94.6us, MfmaUtil 34.6%, conflicts 0.  Pipelining variants
// (dbuf R4, counted-vmcnt R5, ring R8, fine-phase R10) all null/negative:
// inter-block TLP (2-3 blocks/CU) already covers the staging latency.
__global__ __launch_bounds__(256, 2) void moe_gemm_kernel(
    const unsigned short* __restrict__ xbf, const unsigned short* __restrict__ wbf,
    const float* __restrict__ expert_b, const int* __restrict__ counts,
    const int* __restrict__ pair_token, const f32x2* __restrict__ pair_w,
    float* __restrict__ out) {
    const int flat = blockIdx.x;
    const int cls = flat & 7;          // XCD class
    const int nt  = (flat >> 3) & 7;   // n-tile
    const int sup = flat >> 6;
    const int gidx = sup * 8 + cls;    // tile-list index

    __shared__ int hdr[5];             // lo, hi, m_base, cnt, pair
    const int tid = threadIdx.x;
    if (tid < 64) {
        int c = (tid < NPAIR) ? counts[tid * CNT_STRIDE] : 0;
        int ntp = (c + BM - 1) >> 7;              // tiles for this pair
        int s = ntp;
        #pragma unroll
        for (int off = 1; off < 64; off <<= 1) {  // inclusive scan
            int v = __shfl_up(s, off, 64);
            if (tid >= off) s += v;
        }
        int excl = s - ntp;
        bool mine = (tid < NPAIR) && (gidx >= excl) && (gidx < s);
        unsigned long long mb = __ballot(mine);
        int p = mb ? (__ffsll((long long)mb) - 1) : 0;
        int exclp = __shfl(excl, p, 64);
        int cp = __shfl(c, p, 64);
        if (tid == 0) {
            if (mb == 0) { hdr[0] = -1; }
            else {
                int lo = 0, q = p;
                while (q >= 7 - lo) { q -= 7 - lo; ++lo; }
                hdr[0] = lo; hdr[1] = lo + 1 + q;
                hdr[2] = (gidx - exclp) * BM; hdr[3] = cp; hdr[4] = p;
            }
        }
    }
    __syncthreads();
    const int lo = hdr[0];
    if (lo < 0) return;                 // uniform: no tile for this block
    const int hi = hdr[1];
    const int m_base = hdr[2];
    const int cnt = hdr[3];
    const int p = hdr[4];
    const int n_base = nt * BN;

    __shared__ unsigned short As[BM * BK];    // 16 KB each, linear (swizzled content)
    __shared__ unsigned short B0s[BM * BK];
    __shared__ unsigned short B1s[BM * BK];
    __shared__ int tok_s[BM];
    __shared__ f32x2 w_s[BM];

    if (tid < BM) {
        int m = m_base + tid;
        int mc = (m < cnt) ? m : (cnt - 1);  // clamp: garbage rows skipped in epilogue
        tok_s[tid] = pair_token[p * T_TOK + mc];
        w_s[tid]   = pair_w[p * T_TOK + mc];
    }
    __syncthreads();

    const int lane = tid & 63;
    const int w = tid >> 6;
    const int lr = lane & 15, lk = lane >> 4;
    const int wr = w >> 1, wc = w & 1;       // 2x2 waves, 64x64 each

    // staging geometry: wave w, issue i covers rows [i*32+w*8, +8), 128 B each
    const int srow = lane >> 3;                       // row within 8-row group
    const int scol = 8 * ((lane & 7) ^ srow);         // swizzled source column (elems)
    const unsigned short* wb0 = wbf + ((size_t)lo << 20);
    const unsigned short* wb1 = wbf + ((size_t)hi << 20);
    const unsigned short* agp[4];
    const unsigned short* b0gp[4];
    const unsigned short* b1gp[4];
    int loff[4];
    #pragma unroll
    for (int i = 0; i < 4; ++i) {
        int R = i * 32 + w * 8 + srow;
        agp[i]  = xbf + (size_t)tok_s[R] * D_DIM + scol;
        b0gp[i] = wb0 + (size_t)(n_base + R) * D_DIM + scol;
        b1gp[i] = wb1 + (size_t)(n_base + R) * D_DIM + scol;
        loff[i] = (i * 32 + w * 8) * BK;              // wave-uniform LDS elem offset
    }

    f32x4 acc0[4][4] = {};
    f32x4 acc1[4][4] = {};

    for (int k0 = 0; k0 < D_DIM; k0 += BK) {
        #pragma unroll
        for (int i = 0; i < 4; ++i) {
            GLOAD_LDS16(agp[i] + k0, &As[loff[i]]);
            GLOAD_LDS16(b0gp[i] + k0, &B0s[loff[i]]);
            GLOAD_LDS16(b1gp[i] + k0, &B1s[loff[i]]);
        }
        __syncthreads();   // drains vmcnt(0): tile resident
        #pragma unroll
        for (int kk = 0; kk < 2; ++kk) {
            bf16x8 a[4], b[4], c[4];
            #pragma unroll
            for (int m = 0; m < 4; ++m) {
                int R = wr * 64 + m * 16 + lr;
                int cb = (kk * 64 + lk * 16) ^ ((R & 7) << 4);
                a[m] = *(const bf16x8*)((const char*)As + R * 128 + cb);
            }
            #pragma unroll
            for (int n = 0; n < 4; ++n) {
                int R = wc * 64 + n * 16 + lr;
                int cb = (kk * 64 + lk * 16) ^ ((R & 7) << 4);
                b[n] = *(const bf16x8*)((const char*)B0s + R * 128 + cb);
            }
            #pragma unroll
            for (int m = 0; m < 4; ++m)
                #pragma unroll
                for (int n = 0; n < 4; ++n)
                    acc0[m][n] = __builtin_amdgcn_mfma_f32_16x16x32_bf16(a[m], b[n], acc0[m][n], 0, 0, 0);
            #pragma unroll
            for (int n = 0; n < 4; ++n) {
                int R = wc * 64 + n * 16 + lr;
                int cb = (kk * 64 + lk * 16) ^ ((R & 7) << 4);
                c[n] = *(const bf16x8*)((const char*)B1s + R * 128 + cb);
            }
            #pragma unroll
            for (int m = 0; m < 4; ++m)
                #pragma unroll
                for (int n = 0; n < 4; ++n)
                    acc1[m][n] = __builtin_amdgcn_mfma_f32_16x16x32_bf16(a[m], c[n], acc1[m][n], 0, 0, 0);
        }
        __syncthreads();
    }

    // epilogue: out[t, gn] = wl*(acc0+blo) + wh*(acc1+bhi)   (plain stores, no atomics)
    float blo[4], bhi[4];
    #pragma unroll
    for (int n = 0; n < 4; ++n) {
        int gn = n_base + wc * 64 + n * 16 + lr;
        blo[n] = expert_b[lo * D_DIM + gn];
        bhi[n] = expert_b[hi * D_DIM + gn];
    }
    #pragma unroll
    for (int m = 0; m < 4; ++m) {
        #pragma unroll
        for (int j = 0; j < 4; ++j) {
            int mi = wr * 64 + m * 16 + lk * 4 + j;
            if (m_base + mi >= cnt) continue;
            int tk = tok_s[mi];
            f32x2 wgt = w_s[mi];
            size_t obase = (size_t)tk * D_DIM + n_base + wc * 64 + lr;
            #pragma unroll
            for (int n = 0; n < 4; ++n)
                out[obase + n * 16] = wgt[0] * (acc0[m][n][j] + blo[n])
                                    + wgt[1] * (acc1[m][n][j] + bhi[n]);
        }
    }
}

extern "C" void kernel_launch(void* const* d_in, const int* in_sizes, int n_in,
                              void* d_out, int out_size, void* d_ws, size_t ws_size,
                              hipStream_t stream) {
    const float* x        = (const float*)d_in[0];
    const float* gate_w   = (const float*)d_in[1];
    const float* gate_b   = (const float*)d_in[2];
    const float* expert_w = (const float*)d_in[3];
    const float* expert_b = (const float*)d_in[4];

    float* out        = (float*)d_out;                      // [T, D]
    float* out_logits = out + (size_t)T_TOK * D_DIM;        // [T, E]
    float* out_sel    = out_logits + (size_t)T_TOK * E_EXP; // [T, 2] as float

    char* ws = (char*)d_ws;
    unsigned short* wbf = (unsigned short*)ws;                         // 16 MB
    unsigned short* xbf = (unsigned short*)(ws + 16777216);            // 32 MB
    size_t off = 50331648;
    int*   counts     = (int*)(ws + off);                              // 28*64 ints = 7 KB
    int*   pair_token = (int*)(ws + off + 16384);                      // 28*T*4 = 1.75 MB
    f32x2* pair_w     = (f32x2*)(ws + off + 16384 + 1835008);          // 28*T*8 = 3.5 MB

    hipMemsetAsync(counts, 0, NPAIR * CNT_STRIDE * sizeof(int), stream);

    fused_router_kernel<<<RBLK + CBLK, 512, 0, stream>>>(
        x, gate_w, gate_b, out_logits, out_sel, counts, pair_token, pair_w,
        xbf, expert_w, wbf);
    // sup(20) x nt(8) x cls(8): gidx in [0,160), covers max 156 tiles
    moe_gemm_kernel<<<20 * 64, 256, 0, stream>>>(xbf, wbf, expert_b, counts,
                                                 pair_token, pair_w, out);
}

// Round 12
// 130.566 us; speedup vs baseline: 1.3391x; 1.0357x over previous
//
#include <hip/hip_runtime.h>
#include <hip/hip_bf16.h>

#define T_TOK 16384
#define D_DIM 1024
#define E_EXP 8
#define NPAIR 28

#define BM 128
#define BN 64            // halved: 34.7 KB LDS -> 4 blocks/CU
#define BK 64            // 128 B/row in bf16

#define CNT_STRIDE 64    // pad pair counters to 256B apart

typedef __attribute__((ext_vector_type(4))) float f32x4;
typedef __attribute__((ext_vector_type(2))) float f32x2;
typedef __attribute__((ext_vector_type(8))) short bf16x8;
typedef __attribute__((ext_vector_type(4))) unsigned short u16x4;

static __device__ __forceinline__ unsigned short f2bf(float f) {
    unsigned int u = __float_as_uint(f);
    unsigned int r = 0x7FFFu + ((u >> 16) & 1u);
    return (unsigned short)((u + r) >> 16);
}

// direct-to-LDS 16B async copy: global src per-lane, LDS dest = uniform base + lane*16
#define GLOAD_LDS16(gp, lp) \
    __builtin_amdgcn_global_load_lds( \
        (const __attribute__((address_space(1))) void*)(gp), \
        (__attribute__((address_space(3))) void*)(lp), 16, 0, 0)

// ---------------- fused router (blocks 0..255) + expert_w->bf16 (blocks 256..383) ----
#define RTOK 64
#define RBLK 256
#define CBLK 128
__global__ __launch_bounds__(512) void fused_router_kernel(
    const float* __restrict__ x, const float* __restrict__ gate_w,
    const float* __restrict__ gate_b, float* __restrict__ out_logits,
    float* __restrict__ out_sel, int* __restrict__ counts,
    int* __restrict__ pair_token, f32x2* __restrict__ pair_w,
    unsigned short* __restrict__ xbf,
    const float* __restrict__ expert_w, unsigned short* __restrict__ wbf) {
    const int tid = threadIdx.x;
    if (blockIdx.x >= RBLK) {
        // -------- convert region: expert_w fp32 -> bf16 --------
        const int b = blockIdx.x - RBLK;
        const int n4 = (E_EXP * D_DIM * D_DIM) / 4;
        for (int i = b * 512 + tid; i < n4; i += CBLK * 512) {
            f32x4 v = ((const f32x4*)expert_w)[i];
            u16x4 p;
            p[0] = f2bf(v[0]); p[1] = f2bf(v[1]); p[2] = f2bf(v[2]); p[3] = f2bf(v[3]);
            ((u16x4*)wbf)[i] = p;
        }
        return;
    }
    // -------- router region: 64 tokens/block, 8 waves --------
    __shared__ float gw[E_EXP][D_DIM];          // 32 KB
    __shared__ float gb_s[E_EXP];
    __shared__ float logits_s[RTOK][E_EXP];     // 2 KB
    __shared__ int   cnt_local[NPAIR];
    __shared__ int   gbase[NPAIR];
    __shared__ int   ent_p[RTOK];
    __shared__ int   ent_pos[RTOK];
    __shared__ f32x2 ent_w[RTOK];

    for (int i = tid; i < E_EXP * D_DIM; i += 512) gw[0][i] = gate_w[i];
    if (tid < E_EXP) gb_s[tid] = gate_b[tid];
    if (tid < NPAIR) cnt_local[tid] = 0;
    __syncthreads();

    const int lane = tid & 63, wv = tid >> 6;   // 8 waves
    // phase 1: logits via coalesced row streaming (wave per token, 8 tokens/wave)
    for (int j = 0; j < RTOK / 8; ++j) {
        const int jt = wv * (RTOK / 8) + j;
        const int t = blockIdx.x * RTOK + jt;
        const float* xrow = x + (size_t)t * D_DIM;
        unsigned short* xbrow = xbf + (size_t)t * D_DIM;
        float acc[E_EXP] = {};
        #pragma unroll
        for (int c = 0; c < 4; ++c) {
            const int col = c * 256 + lane * 4;
            f32x4 xv = *(const f32x4*)(xrow + col);
            u16x4 pk;
            pk[0] = f2bf(xv[0]); pk[1] = f2bf(xv[1]); pk[2] = f2bf(xv[2]); pk[3] = f2bf(xv[3]);
            *(u16x4*)(xbrow + col) = pk;
            #pragma unroll
            for (int e = 0; e < E_EXP; ++e) {
                f32x4 gv = *(const f32x4*)(&gw[e][col]);
                acc[e] += xv[0] * gv[0] + xv[1] * gv[1] + xv[2] * gv[2] + xv[3] * gv[3];
            }
        }
        #pragma unroll
        for (int e = 0; e < E_EXP; ++e) {
            float v = acc[e];
            #pragma unroll
            for (int off = 32; off > 0; off >>= 1) v += __shfl_xor(v, off, 64);
            acc[e] = v;
        }
        if (lane == 0) {
            #pragma unroll
            for (int e = 0; e < E_EXP; ++e) logits_s[jt][e] = acc[e] + gb_s[e];
        }
    }
    __syncthreads();
    // phase 2: one thread per token: softmax, top-2, pair bookkeeping
    if (tid < RTOK) {
        const int t = blockIdx.x * RTOK + tid;
        float l[E_EXP], p[E_EXP];
        float m = -1e30f;
        #pragma unroll
        for (int e = 0; e < E_EXP; ++e) { l[e] = logits_s[tid][e]; m = fmaxf(m, l[e]); }
        float s = 0.f;
        #pragma unroll
        for (int e = 0; e < E_EXP; ++e) { p[e] = expf(l[e] - m); s += p[e]; }
        #pragma unroll
        for (int e = 0; e < E_EXP; ++e) p[e] /= s;
        // top-2 on probs, strict > => lowest index wins ties (matches jax.lax.top_k)
        int e0 = 0; float p0 = p[0];
        #pragma unroll
        for (int e = 1; e < E_EXP; ++e) if (p[e] > p0) { p0 = p[e]; e0 = e; }
        int e1 = -1; float p1 = -1e30f;
        #pragma unroll
        for (int e = 0; e < E_EXP; ++e) if (e != e0 && p[e] > p1) { p1 = p[e]; e1 = e; }
        float denom = p0 + p1;
        float w0 = p0 / denom, w1 = p1 / denom;
        out_sel[t * 2 + 0] = (float)e0;
        out_sel[t * 2 + 1] = (float)e1;
        int lo = min(e0, e1), hi = max(e0, e1);
        float wl = (e0 < e1) ? w0 : w1;
        float wh = (e0 < e1) ? w1 : w0;
        int pp = (lo * (15 - lo)) / 2 + (hi - lo - 1);   // triangular index [0,28)
        int pos = atomicAdd(&cnt_local[pp], 1);          // LDS atomic: cheap
        ent_p[tid] = pp; ent_pos[tid] = pos;
        f32x2 wv2; wv2[0] = wl; wv2[1] = wh;
        ent_w[tid] = wv2;
    }
    __syncthreads();
    if (tid < NPAIR) gbase[tid] = atomicAdd(&counts[tid * CNT_STRIDE], cnt_local[tid]);
    if (tid < RTOK * E_EXP / 4) {
        f32x4 v = ((const f32x4*)&logits_s[0][0])[tid];
        ((f32x4*)(out_logits + (size_t)blockIdx.x * RTOK * E_EXP))[tid] = v;
    }
    __syncthreads();
    if (tid < RTOK) {
        int pp = ent_p[tid];
        int pos = gbase[pp] + ent_pos[tid];
        pair_token[pp * T_TOK + pos] = blockIdx.x * RTOK + tid;
        pair_w[pp * T_TOK + pos] = ent_w[tid];
    }
}

// ---------------- pair-grouped GEMM: BN=64 (4 blocks/CU) + XCD pair-chunking --------
// out[t] = wl*(Wlo x+blo) + wh*(Whi x+bhi).  Single-buffer BK=64 (K-loop schedule
// FROZEN per R4/R5/R8/R10 nulls); both-sides XOR swizzle; plain stores.
// New vs R11: (1) BN=64 -> LDS 34.7 KB -> 4 blocks/CU (TLP, not pipelining);
// (2) gidx = cls*chunk+sup, chunk=ceil(ntiles/8): each XCD gets a CONTIGUOUS
// slice of the pair-major tile list -> one pair's weights (4MB) live in one
// XCD's L2 instead of being re-fetched by all 8.
__global__ __launch_bounds__(256, 2) void moe_gemm_kernel(
    const unsigned short* __restrict__ xbf, const unsigned short* __restrict__ wbf,
    const float* __restrict__ expert_b, const int* __restrict__ counts,
    const int* __restrict__ pair_token, const f32x2* __restrict__ pair_w,
    float* __restrict__ out) {
    const int flat = blockIdx.x;
    const int cls = flat & 7;           // XCD class (flat % 8 round-robin)
    const int nt  = (flat >> 3) & 15;   // n-tile [0,16)
    const int sup = flat >> 7;          // [0,20)

    __shared__ int hdr[5];              // lo, hi, m_base, cnt, pair
    const int tid = threadIdx.x;
    if (tid < 64) {
        int c = (tid < NPAIR) ? counts[tid * CNT_STRIDE] : 0;
        int ntp = (c + BM - 1) >> 7;              // m-tiles for this pair
        int s = ntp;
        #pragma unroll
        for (int off = 1; off < 64; off <<= 1) {  // inclusive scan
            int v = __shfl_up(s, off, 64);
            if (tid >= off) s += v;
        }
        int excl = s - ntp;
        int ntot = __shfl(s, NPAIR - 1, 64);      // total tiles
        int chunk = (ntot + 7) >> 3;              // per-XCD contiguous slice
        int gidx = cls * chunk + sup;
        bool valid = (sup < chunk) && (gidx < ntot);
        bool mine = valid && (tid < NPAIR) && (gidx >= excl) && (gidx < s);
        unsigned long long mb = __ballot(mine);
        int p = mb ? (__ffsll((long long)mb) - 1) : 0;
        int exclp = __shfl(excl, p, 64);
        int cp = __shfl(c, p, 64);
        if (tid == 0) {
            if (mb == 0) { hdr[0] = -1; }
            else {
                int lo = 0, q = p;
                while (q >= 7 - lo) { q -= 7 - lo; ++lo; }
                hdr[0] = lo; hdr[1] = lo + 1 + q;
                hdr[2] = (gidx - exclp) * BM; hdr[3] = cp; hdr[4] = p;
            }
        }
    }
    __syncthreads();
    const int lo = hdr[0];
    if (lo < 0) return;                 // uniform: no tile for this block
    const int hi = hdr[1];
    const int m_base = hdr[2];
    const int cnt = hdr[3];
    const int p = hdr[4];
    const int n_base = nt * BN;

    __shared__ unsigned short As[BM * BK];    // 16 KB, linear (swizzled content)
    __shared__ unsigned short B0s[BN * BK];   // 8 KB each
    __shared__ unsigned short B1s[BN * BK];
    __shared__ int tok_s[BM];
    __shared__ f32x2 w_s[BM];

    if (tid < BM) {
        int m = m_base + tid;
        int mc = (m < cnt) ? m : (cnt - 1);  // clamp: garbage rows skipped in epilogue
        tok_s[tid] = pair_token[p * T_TOK + mc];
        w_s[tid]   = pair_w[p * T_TOK + mc];
    }
    __syncthreads();

    const int lane = tid & 63;
    const int w = tid >> 6;
    const int lr = lane & 15, lk = lane >> 4;
    const int wm = w >> 1, wn = w & 1;       // 2x2 waves, wave tile 64(m) x 32(n)

    // staging geometry: wave w, issue i covers rows [i*32+w*8, +8), 128 B each
    const int srow = lane >> 3;                       // row within 8-row group
    const int scol = 8 * ((lane & 7) ^ srow);         // swizzled source column (elems)
    const unsigned short* wb0 = wbf + ((size_t)lo << 20);
    const unsigned short* wb1 = wbf + ((size_t)hi << 20);
    const unsigned short* agp[4];
    const unsigned short* b0gp[2];
    const unsigned short* b1gp[2];
    int loffA[4], loffB[2];
    #pragma unroll
    for (int i = 0; i < 4; ++i) {
        int R = i * 32 + w * 8 + srow;
        agp[i]  = xbf + (size_t)tok_s[R] * D_DIM + scol;
        loffA[i] = (i * 32 + w * 8) * BK;             // wave-uniform LDS elem offset
    }
    #pragma unroll
    for (int i = 0; i < 2; ++i) {
        int R = i * 32 + w * 8 + srow;                // B rows [0,64)
        b0gp[i] = wb0 + (size_t)(n_base + R) * D_DIM + scol;
        b1gp[i] = wb1 + (size_t)(n_base + R) * D_DIM + scol;
        loffB[i] = (i * 32 + w * 8) * BK;
    }

    f32x4 acc0[4][2] = {};
    f32x4 acc1[4][2] = {};

    for (int k0 = 0; k0 < D_DIM; k0 += BK) {
        #pragma unroll
        for (int i = 0; i < 4; ++i) GLOAD_LDS16(agp[i] + k0, &As[loffA[i]]);
        #pragma unroll
        for (int i = 0; i < 2; ++i) {
            GLOAD_LDS16(b0gp[i] + k0, &B0s[loffB[i]]);
            GLOAD_LDS16(b1gp[i] + k0, &B1s[loffB[i]]);
        }
        __syncthreads();   // drains vmcnt(0): tile resident
        #pragma unroll
        for (int kk = 0; kk < 2; ++kk) {
            bf16x8 a[4], b[2], c[2];
            #pragma unroll
            for (int m = 0; m < 4; ++m) {
                int R = wm * 64 + m * 16 + lr;
                int cb = (kk * 64 + lk * 16) ^ ((R & 7) << 4);
                a[m] = *(const bf16x8*)((const char*)As + R * 128 + cb);
            }
            #pragma unroll
            for (int n = 0; n < 2; ++n) {
                int R = wn * 32 + n * 16 + lr;
                int cb = (kk * 64 + lk * 16) ^ ((R & 7) << 4);
                b[n] = *(const bf16x8*)((const char*)B0s + R * 128 + cb);
                c[n] = *(const bf16x8*)((const char*)B1s + R * 128 + cb);
            }
            #pragma unroll
            for (int m = 0; m < 4; ++m)
                #pragma unroll
                for (int n = 0; n < 2; ++n)
                    acc0[m][n] = __builtin_amdgcn_mfma_f32_16x16x32_bf16(a[m], b[n], acc0[m][n], 0, 0, 0);
            #pragma unroll
            for (int m = 0; m < 4; ++m)
                #pragma unroll
                for (int n = 0; n < 2; ++n)
                    acc1[m][n] = __builtin_amdgcn_mfma_f32_16x16x32_bf16(a[m], c[n], acc1[m][n], 0, 0, 0);
        }
        __syncthreads();
    }

    // epilogue: out[t, gn] = wl*(acc0+blo) + wh*(acc1+bhi)   (plain stores, no atomics)
    float blo[2], bhi[2];
    #pragma unroll
    for (int n = 0; n < 2; ++n) {
        int gn = n_base + wn * 32 + n * 16 + lr;
        blo[n] = expert_b[lo * D_DIM + gn];
        bhi[n] = expert_b[hi * D_DIM + gn];
    }
    #pragma unroll
    for (int m = 0; m < 4; ++m) {
        #pragma unroll
        for (int j = 0; j < 4; ++j) {
            int mi = wm * 64 + m * 16 + lk * 4 + j;
            if (m_base + mi >= cnt) continue;
            int tk = tok_s[mi];
            f32x2 wgt = w_s[mi];
            size_t obase = (size_t)tk * D_DIM + n_base + wn * 32 + lr;
            #pragma unroll
            for (int n = 0; n < 2; ++n)
                out[obase + n * 16] = wgt[0] * (acc0[m][n][j] + blo[n])
                                    + wgt[1] * (acc1[m][n][j] + bhi[n]);
        }
    }
}

extern "C" void kernel_launch(void* const* d_in, const int* in_sizes, int n_in,
                              void* d_out, int out_size, void* d_ws, size_t ws_size,
                              hipStream_t stream) {
    const float* x        = (const float*)d_in[0];
    const float* gate_w   = (const float*)d_in[1];
    const float* gate_b   = (const float*)d_in[2];
    const float* expert_w = (const float*)d_in[3];
    const float* expert_b = (const float*)d_in[4];

    float* out        = (float*)d_out;                      // [T, D]
    float* out_logits = out + (size_t)T_TOK * D_DIM;        // [T, E]
    float* out_sel    = out_logits + (size_t)T_TOK * E_EXP; // [T, 2] as float

    char* ws = (char*)d_ws;
    unsigned short* wbf = (unsigned short*)ws;                         // 16 MB
    unsigned short* xbf = (unsigned short*)(ws + 16777216);            // 32 MB
    size_t off = 50331648;
    int*   counts     = (int*)(ws + off);                              // 28*64 ints = 7 KB
    int*   pair_token = (int*)(ws + off + 16384);                      // 28*T*4 = 1.75 MB
    f32x2* pair_w     = (f32x2*)(ws + off + 16384 + 1835008);          // 28*T*8 = 3.5 MB

    hipMemsetAsync(counts, 0, NPAIR * CNT_STRIDE * sizeof(int), stream);

    fused_router_kernel<<<RBLK + CBLK, 512, 0, stream>>>(
        x, gate_w, gate_b, out_logits, out_sel, counts, pair_token, pair_w,
        xbf, expert_w, wbf);
    // sup(20) x nt(16) x cls(8) = 2560 blocks; chunk=ceil(ntiles/8)<=20 covered
    moe_gemm_kernel<<<20 * 16 * 8, 256, 0, stream>>>(xbf, wbf, expert_b, counts,
                                                     pair_token, pair_w, out);
}